// Round 1
// baseline (98.743 us; speedup 1.0000x reference)
//
#include <hip/hip_runtime.h>
#include <math.h>

#define DD 256
#define NTHREADS 256

__global__ __launch_bounds__(NTHREADS) void dxent_kernel(
    const float* __restrict__ m,
    const float* __restrict__ k,
    const int* __restrict__ idx,
    float* __restrict__ out)
{
    const int b = blockIdx.x;
    const int t = threadIdx.x;
    const int lane = t & 63;
    const int wave = t >> 6;

    const float* mrow = m + (size_t)b * DD;
    const float* kmat = k + (size_t)b * DD * DD;

    __shared__ float p_s[DD];
    __shared__ float red_s[8];

    // ---- softmax over m[b, :] (one element per thread) ----
    float mv = mrow[t];

    // wave max (64 lanes)
    float x = mv;
    #pragma unroll
    for (int off = 32; off >= 1; off >>= 1)
        x = fmaxf(x, __shfl_xor(x, off));
    if (lane == 0) red_s[wave] = x;
    __syncthreads();
    float rowmax = fmaxf(fmaxf(red_s[0], red_s[1]), fmaxf(red_s[2], red_s[3]));

    float e = expf(mv - rowmax);
    float s = e;
    #pragma unroll
    for (int off = 32; off >= 1; off >>= 1)
        s += __shfl_xor(s, off);
    if (lane == 0) red_s[4 + wave] = s;
    __syncthreads();
    float sum = red_s[4] + red_s[5] + red_s[6] + red_s[7];
    float pj = e * (1.0f / sum);
    p_s[t] = pj;
    __syncthreads();

    // ---- contraction: wave w handles rows w, w+4, ..., w+252; lane l handles cols 4l..4l+3 ----
    const int cg = lane * 4;              // column group base
    float4 qacc = make_float4(0.f, 0.f, 0.f, 0.f);
    float tacc = 0.f;

    for (int rb = 0; rb < DD; rb += 4) {
        const int r = rb + wave;
        const float pr = p_s[r];          // broadcast within wave
        const float4 v = *reinterpret_cast<const float4*>(&kmat[(size_t)r * DD + cg]);
        qacc.x = fmaf(v.x, pr, qacc.x);
        qacc.y = fmaf(v.y, pr, qacc.y);
        qacc.z = fmaf(v.z, pr, qacc.z);
        qacc.w = fmaf(v.w, pr, qacc.w);
        const int d = r - cg;
        if ((unsigned)d < 4u) {           // diagonal element k[r,r] is in this float4
            const float dv = (d == 0) ? v.x : (d == 1) ? v.y : (d == 2) ? v.z : v.w;
            tacc = fmaf(dv, pr, tacc);
        }
    }

    const float4 pc = *reinterpret_cast<const float4*>(&p_s[cg]);
    float q = qacc.x * pc.x + qacc.y * pc.y + qacc.z * pc.z + qacc.w * pc.w;
    float tr = tacc;

    #pragma unroll
    for (int off = 32; off >= 1; off >>= 1) {
        q  += __shfl_xor(q, off);
        tr += __shfl_xor(tr, off);
    }
    __syncthreads();   // all prior red_s reads are done (they precede the p_s barrier)
    if (lane == 0) { red_s[wave] = q; red_s[4 + wave] = tr; }
    __syncthreads();

    if (t == 0) {
        const float qt = red_s[0] + red_s[1] + red_s[2] + red_s[3];
        const float tt = red_s[4] + red_s[5] + red_s[6] + red_s[7];
        const float lse = rowmax + logf(sum);
        const float picked = mrow[idx[b]];
        out[b] = lse - picked + 0.5f * (tt - qt);
    }
}

extern "C" void kernel_launch(void* const* d_in, const int* in_sizes, int n_in,
                              void* d_out, int out_size, void* d_ws, size_t ws_size,
                              hipStream_t stream) {
    const float* m = (const float*)d_in[0];
    const float* k = (const float*)d_in[1];
    const int* idx = (const int*)d_in[2];
    float* out = (float*)d_out;

    const int B = out_size;   // 2048
    dxent_kernel<<<B, NTHREADS, 0, stream>>>(m, k, idx, out);
}